// Round 10
// baseline (3988.459 us; speedup 1.0000x reference)
//
#include <hip/hip_runtime.h>
#include <stdint.h>

typedef __bf16 bf16_t;
typedef __bf16 bf16x8 __attribute__((ext_vector_type(8)));
typedef float  f32x4  __attribute__((ext_vector_type(4)));
typedef unsigned long long u64_t;

union Frag { uint32_t u[4]; u64_t d[2]; bf16x8 v; };

struct WPtrs {
    const float* Wi[4];
    const float* Wh[4];
    const float* bi[4];
    const float* bh[4];
};

#define LOG2E 1.44269504088896340736f

// Gate pre-activations arrive PRE-SCALED: i,f,o by log2e; g by 2*log2e
// (folded into bf16 weights + biases). Shared-rcp cell algebra (r8-verified).
__device__ __forceinline__ float cell_c(float gi, float gf, float gg, float c) {
    const float ef = __builtin_amdgcn_exp2f(-gf);
    const float ei = __builtin_amdgcn_exp2f(-gi);
    const float Eg = __builtin_amdgcn_exp2f(gg);
    const float pf = 1.0f + ef, pi = 1.0f + ei;
    const float pg = Eg + 1.0f, mg = Eg - 1.0f;
    const float num = c * pi * pg + mg * pf;
    const float den = pf * pi * pg;
    return num * __builtin_amdgcn_rcpf(den);
}
__device__ __forceinline__ float cell_h(float go, float c) {
    const float Ec = __builtin_amdgcn_exp2f(c * (2.0f * LOG2E));
    const float eo = __builtin_amdgcn_exp2f(-go);
    const float num = Ec - 1.0f;
    const float den = (1.0f + eo) * (Ec + 1.0f);
    return num * __builtin_amdgcn_rcpf(den);
}

// lgkm-only phase barrier (keeps global loads in flight across it).
__device__ __forceinline__ void phase_barrier() {
    asm volatile("s_waitcnt lgkmcnt(0)" ::: "memory");
    __builtin_amdgcn_s_barrier();
    asm volatile("" ::: "memory");
}

__device__ __forceinline__ void wait_flag(const int* f, int need) {
    while (__hip_atomic_load(f, __ATOMIC_ACQUIRE, __HIP_MEMORY_SCOPE_AGENT) < need)
        __builtin_amdgcn_s_sleep(8);
}

// r10: pad-free 4-layer LSTM as a 2-block producer/consumer pipeline.
// 128 tiles x 16 REAL batch cols (MFMA N=16 fully used -> MFMA pipe halves).
// 256 blocks x 512 thr: block = (tile = bid>>1, half = bid&1):
//   half0 = layers {0,1} (producer), half1 = {2,3} (consumer).
//   8 waves = 2 layers x 4 unit-quarters; 4 REAL cells/lane (no pad, no DPP;
//   bias back in the MFMA C operand).
// Intra-block layer exchange: LDS (HW-verified D->B frag identity, r1-r8).
// Cross-block boundary (layer1 -> layer2): full-sequence global ring
// [tile][t][lane][uq] u64, written with RELAXED/AGENT 8B atomics (coherent at
// LLC, no L2 wb/inv needed) + produced[tile] flag (RELEASE after per-wave
// vmcnt(0) drain + block barrier / ACQUIRE poll on consumer). Consumer
// prefetches slot t+1 one phase ahead into registers (latency hidden).
// Deadlock-safe: 256 blocks always co-resident (1 or 2 blocks/CU both cover
// all 256); flags reset each launch via hipMemsetAsync; full-seq ring -> no
// backpressure needed.
__global__ __launch_bounds__(512, 2)
void lstm_pipe(const float* __restrict__ x0, float* __restrict__ last_out,
               const WPtrs wp, u64_t* __restrict__ ring, int* __restrict__ produced)
{
    const int bid  = blockIdx.x;
    const int tile = bid >> 1;           // 0..127 (16 batch rows each)
    const int half = bid & 1;            // 0: layers 0,1 ; 1: layers 2,3
    const int tid  = threadIdx.x;
    const int w    = tid >> 6;           // 0..7
    const int lane = tid & 63;
    const int l15  = lane & 15;          // batch col (REAL)
    const int l4   = lane >> 4;
    const int ll   = w >> 2;             // local layer 0/1
    const int uq   = w & 3;              // unit quarter
    const int l    = half * 2 + ll;      // global layer

    // [buf][local layer][lane][uq 0..3 + 2 pad] ; 12 KB
    __shared__ uint2 lds_h[2][2][64][6];
    for (int i = tid; i < 2 * 2 * 64 * 6; i += 512)
        ((uint2*)lds_h)[i] = make_uint2(0u, 0u);

    const float* Wi = wp.Wi[l];
    const float* Wh = wp.Wh[l];
    const float gs[4] = {LOG2E, LOG2E, 2.0f * LOG2E, LOG2E};

    // ---- weight A-fragments (HW-verified lane map) ----
    bf16x8 whA[4][2];
    bf16x8 wiA[4][2];
#pragma unroll
    for (int G = 0; G < 4; ++G) {
        const float sc = gs[G];
        const int row = G * 64 + 16 * uq + l15;
        const float* r = Wh + (size_t)row * 64;
#pragma unroll
        for (int s = 0; s < 2; ++s) {
            f32x4 a = *(const f32x4*)(r + 32 * s + 4 * l4);
            f32x4 b = *(const f32x4*)(r + 32 * s + 4 * l4 + 16);
            bf16x8 f;
            f[0] = (bf16_t)(a[0] * sc); f[1] = (bf16_t)(a[1] * sc);
            f[2] = (bf16_t)(a[2] * sc); f[3] = (bf16_t)(a[3] * sc);
            f[4] = (bf16_t)(b[0] * sc); f[5] = (bf16_t)(b[1] * sc);
            f[6] = (bf16_t)(b[2] * sc); f[7] = (bf16_t)(b[3] * sc);
            whA[G][s] = f;
        }
        if (l == 0) {
            const float* ri = Wi + (size_t)row * 18;     // K=18 padded to 32
            const int k0 = 4 * l4;
            bf16x8 f;
            f[0] = (bf16_t)(ri[k0 + 0] * sc); f[1] = (bf16_t)(ri[k0 + 1] * sc);
            f[2] = (bf16_t)(ri[k0 + 2] * sc); f[3] = (bf16_t)(ri[k0 + 3] * sc);
            f[4] = (l4 == 0) ? (bf16_t)(ri[16] * sc) : (bf16_t)0.0f;
            f[5] = (l4 == 0) ? (bf16_t)(ri[17] * sc) : (bf16_t)0.0f;
            f[6] = (bf16_t)0.0f; f[7] = (bf16_t)0.0f;
            wiA[G][0] = f;
            wiA[G][1] = f;    // dead for l==0; [2][1]/[3][1] alias the x buffers
        } else {
            const float* ri = Wi + (size_t)row * 64;
#pragma unroll
            for (int s = 0; s < 2; ++s) {
                f32x4 a = *(const f32x4*)(ri + 32 * s + 4 * l4);
                f32x4 b = *(const f32x4*)(ri + 32 * s + 4 * l4 + 16);
                bf16x8 f;
                f[0] = (bf16_t)(a[0] * sc); f[1] = (bf16_t)(a[1] * sc);
                f[2] = (bf16_t)(a[2] * sc); f[3] = (bf16_t)(a[3] * sc);
                f[4] = (bf16_t)(b[0] * sc); f[5] = (bf16_t)(b[1] * sc);
                f[6] = (bf16_t)(b[2] * sc); f[7] = (bf16_t)(b[3] * sc);
                wiA[G][s] = f;
            }
        }
    }

    // ---- bias as MFMA C operand: rows 4*l4+0..3 ----
    f32x4 bias[4];
#pragma unroll
    for (int G = 0; G < 4; ++G) {
        const int rb = G * 64 + 16 * uq + 4 * l4;
        f32x4 u = *(const f32x4*)(wp.bi[l] + rb);
        f32x4 v = *(const f32x4*)(wp.bh[l] + rb);
        bias[G] = (u + v) * gs[G];
    }

    // ---- ring addressing: [tile][t][lane][uq] u64 ----
    u64_t* rt = ring + (size_t)tile * 512 * 256;

    // ---- x prefetch (layer 0 only), aliased onto dead wiA slots ----
    bf16x8& xfA = wiA[2][1];
    bf16x8& xfB = wiA[3][1];
    const float* xrow = x0 + (size_t)(tile * 16 + l15) * (512 * 18);
    auto loadx = [&](int t, bf16x8& dst) {
        const float* xr = xrow + t * 18;
        const int k0 = 4 * l4;
        bf16x8 f;
        f[0] = (bf16_t)xr[k0 + 0]; f[1] = (bf16_t)xr[k0 + 1];
        f[2] = (bf16_t)xr[k0 + 2]; f[3] = (bf16_t)xr[k0 + 3];
        f[4] = (l4 == 0) ? (bf16_t)xr[16] : (bf16_t)0.0f;
        f[5] = (l4 == 0) ? (bf16_t)xr[17] : (bf16_t)0.0f;
        f[6] = (bf16_t)0.0f; f[7] = (bf16_t)0.0f;
        dst = f;
    };

    u64_t rA[4] = {0, 0, 0, 0}, rB[4] = {0, 0, 0, 0};   // consumer prefetch regs

    if (half == 0 && ll == 0) { loadx(0, xfA); loadx(1, xfB); }
    if (half == 1 && ll == 0) {
        wait_flag(&produced[tile], 1);
#pragma unroll
        for (int k = 0; k < 4; ++k)
            rA[k] = __hip_atomic_load(rt + (size_t)lane * 4 + k,
                                      __ATOMIC_RELAXED, __HIP_MEMORY_SCOPE_AGENT);
    }

    f32x4 c = {0.0f, 0.0f, 0.0f, 0.0f};    // 4 cells/lane
    f32x4 last_h = {0.0f, 0.0f, 0.0f, 0.0f};

    __syncthreads();

    auto lds_frags = [&](int br, int lll, Frag& f0, Frag& f1) {
        uint4 q0 = *(const uint4*)&lds_h[br][lll][lane][0];
        uint4 q1 = *(const uint4*)&lds_h[br][lll][lane][2];
        f0.u[0] = q0.x; f0.u[1] = q0.y; f0.u[2] = q0.z; f0.u[3] = q0.w;
        f1.u[0] = q1.x; f1.u[1] = q1.y; f1.u[2] = q1.z; f1.u[3] = q1.w;
    };
    auto own_h_mfma = [&](f32x4 (&acc)[4], int br, int lll) {
        Frag h0, h1; lds_frags(br, lll, h0, h1);
#pragma unroll
        for (int G = 0; G < 4; ++G)
            acc[G] = __builtin_amdgcn_mfma_f32_16x16x32_bf16(whA[G][0], h0.v, acc[G], 0, 0, 0);
#pragma unroll
        for (int G = 0; G < 4; ++G)
            acc[G] = __builtin_amdgcn_mfma_f32_16x16x32_bf16(whA[G][1], h1.v, acc[G], 0, 0, 0);
    };
    auto in_mfma = [&](f32x4 (&acc)[4], const Frag& b0, const Frag& b1) {
#pragma unroll
        for (int G = 0; G < 4; ++G)
            acc[G] = __builtin_amdgcn_mfma_f32_16x16x32_bf16(wiA[G][0], b0.v, bias[G], 0, 0, 0);
#pragma unroll
        for (int G = 0; G < 4; ++G)
            acc[G] = __builtin_amdgcn_mfma_f32_16x16x32_bf16(wiA[G][1], b1.v, acc[G], 0, 0, 0);
    };
    auto cell_tail = [&](f32x4 (&acc)[4], int bw, int lll) -> u64_t {
        union { u64_t u8; uint2 u2; bf16_t b[4]; } pk;
#pragma unroll
        for (int i = 0; i < 4; ++i) {
            c[i] = cell_c(acc[0][i], acc[1][i], acc[2][i], c[i]);
            const float h = cell_h(acc[3][i], c[i]);
            pk.b[i] = (bf16_t)h;
            last_h[i] = h;
        }
        lds_h[bw][lll][lane][uq] = pk.u2;
        return pk.u8;
    };

    if (half == 0) {
        // ================= producer half: layers 0,1 =================
        auto ph0 = [&](int p, int br, int bw, bf16x8& xf) {
            if (tid == 256 && p >= 2)       // publish h^1_{p-2} (drained last phase)
                __hip_atomic_store(&produced[tile], p - 1,
                                   __ATOMIC_RELEASE, __HIP_MEMORY_SCOPE_AGENT);
            if (ll == 0) {
                const int t = p;
                if (t < 512) {
                    f32x4 acc[4];
#pragma unroll
                    for (int G = 0; G < 4; ++G)
                        acc[G] = __builtin_amdgcn_mfma_f32_16x16x32_bf16(
                            wiA[G][0], xf, bias[G], 0, 0, 0);
                    loadx((t + 2 < 512) ? t + 2 : 511, xf);
                    own_h_mfma(acc, br, 0);
                    cell_tail(acc, bw, 0);
                }
            } else {
                const int t = p - 1;
                if ((unsigned)t < 512u) {
                    Frag b0, b1; lds_frags(br, 0, b0, b1);   // layer0 h_t
                    f32x4 acc[4];
                    in_mfma(acc, b0, b1);
                    own_h_mfma(acc, br, 1);
                    const u64_t h8 = cell_tail(acc, bw, 1);
                    __hip_atomic_store(rt + (size_t)t * 256 + (size_t)lane * 4 + uq,
                                       h8, __ATOMIC_RELAXED, __HIP_MEMORY_SCOPE_AGENT);
                    asm volatile("s_waitcnt vmcnt(0)" ::: "memory");
                }
            }
            phase_barrier();
        };
        for (int p = 0; p < 514; p += 2) { ph0(p, 1, 0, xfA); ph0(p + 1, 0, 1, xfB); }
    } else {
        // ================= consumer half: layers 2,3 =================
        auto ph1 = [&](int q, int br, int bw, u64_t (&cur)[4], u64_t (&nxt)[4]) {
            if (ll == 0) {
                const int t = q;
                if (t < 512) {
                    if (t + 1 < 512) {
                        wait_flag(&produced[tile], t + 2);
#pragma unroll
                        for (int k = 0; k < 4; ++k)
                            nxt[k] = __hip_atomic_load(
                                rt + (size_t)(t + 1) * 256 + (size_t)lane * 4 + k,
                                __ATOMIC_RELAXED, __HIP_MEMORY_SCOPE_AGENT);
                    }
                    Frag b0, b1;
                    b0.d[0] = cur[0]; b0.d[1] = cur[1];
                    b1.d[0] = cur[2]; b1.d[1] = cur[3];
                    f32x4 acc[4];
                    in_mfma(acc, b0, b1);
                    own_h_mfma(acc, br, 0);
                    cell_tail(acc, bw, 0);
                }
            } else {
                const int t = q - 1;
                if ((unsigned)t < 512u) {
                    Frag b0, b1; lds_frags(br, 0, b0, b1);   // layer2 h_t
                    f32x4 acc[4];
                    in_mfma(acc, b0, b1);
                    own_h_mfma(acc, br, 1);
                    cell_tail(acc, bw, 1);
                    if (t == 511) {
                        float* o = last_out + (size_t)(tile * 16 + l15) * 64
                                   + 16 * uq + 4 * l4;
                        *(f32x4*)o = last_h;
                    }
                }
            }
            phase_barrier();
        };
        for (int q = 0; q < 514; q += 2) { ph1(q, 1, 0, rA, rB); ph1(q + 1, 0, 1, rB, rA); }
    }
}

// out = relu(last @ W1^T + b1) @ W2^T + b2   (f32, tiny)
__global__ __launch_bounds__(256)
void mlp_head(const float* __restrict__ last,
              const float* __restrict__ W1, const float* __restrict__ b1,
              const float* __restrict__ W2, const float* __restrict__ b2,
              float* __restrict__ out)
{
    __shared__ float sW1[128 * 64];
    __shared__ float sb1[128];
    __shared__ float sW2[3 * 128];
    __shared__ float sb2[4];
    const int tid = threadIdx.x;
    for (int i = tid; i < 128 * 64; i += 256) sW1[i] = W1[i];
    for (int i = tid; i < 128; i += 256) sb1[i] = b1[i];
    for (int i = tid; i < 3 * 128; i += 256) sW2[i] = W2[i];
    if (tid < 3) sb2[tid] = b2[tid];
    __syncthreads();

    const int b = blockIdx.x * 256 + tid;
    const float* lb = last + (size_t)b * 64;
    float xv[64];
#pragma unroll
    for (int k = 0; k < 64; k += 4) {
        f32x4 v = *(const f32x4*)(lb + k);
        xv[k] = v[0]; xv[k + 1] = v[1]; xv[k + 2] = v[2]; xv[k + 3] = v[3];
    }
    float o0 = sb2[0], o1 = sb2[1], o2 = sb2[2];
    for (int j = 0; j < 128; ++j) {
        float a = sb1[j];
        const float* wr = &sW1[j * 64];
#pragma unroll
        for (int k = 0; k < 64; k += 4) {
            f32x4 wv = *(const f32x4*)(wr + k);
            a += xv[k] * wv[0] + xv[k + 1] * wv[1] + xv[k + 2] * wv[2] + xv[k + 3] * wv[3];
        }
        a = fmaxf(a, 0.0f);
        o0 += a * sW2[0 * 128 + j];
        o1 += a * sW2[1 * 128 + j];
        o2 += a * sW2[2 * 128 + j];
    }
    out[(size_t)b * 3 + 0] = o0;
    out[(size_t)b * 3 + 1] = o1;
    out[(size_t)b * 3 + 2] = o2;
}

extern "C" void kernel_launch(void* const* d_in, const int* in_sizes, int n_in,
                              void* d_out, int out_size, void* d_ws, size_t ws_size,
                              hipStream_t stream)
{
    (void)in_sizes; (void)n_in; (void)out_size; (void)ws_size;

    const float* x = (const float*)d_in[0];
    WPtrs wp;
    for (int l = 0; l < 4; ++l) {
        wp.Wi[l] = (const float*)d_in[1 + 4 * l + 0];
        wp.Wh[l] = (const float*)d_in[1 + 4 * l + 1];
        wp.bi[l] = (const float*)d_in[1 + 4 * l + 2];
        wp.bh[l] = (const float*)d_in[1 + 4 * l + 3];
    }
    const float* W1 = (const float*)d_in[17];
    const float* b1 = (const float*)d_in[18];
    const float* W2 = (const float*)d_in[19];
    const float* b2 = (const float*)d_in[20];

    // ws layout: last (512 KiB f32) | ring (128 MiB) | produced flags (512 B)
    char* ws = (char*)d_ws;
    float* last     = (float*)ws;
    u64_t* ring     = (u64_t*)(ws + (size_t)524288);
    int*   produced = (int*)(ws + (size_t)524288 + (size_t)134217728);

    hipMemsetAsync(produced, 0, 512, stream);   // reset flags EVERY launch (graph replay)
    lstm_pipe<<<dim3(256), dim3(512), 0, stream>>>(x, last, wp, ring, produced);
    mlp_head<<<dim3(8), dim3(256), 0, stream>>>(last, W1, b1, W2, b2, (float*)d_out);
}

// Round 11
// 660.412 us; speedup vs baseline: 6.0394x; 6.0394x over previous
//
#include <hip/hip_runtime.h>
#include <stdint.h>

typedef __bf16 bf16_t;
typedef __bf16 bf16x8 __attribute__((ext_vector_type(8)));
typedef float  f32x4  __attribute__((ext_vector_type(4)));

union Frag { uint32_t u[4]; bf16x8 v; };

struct WPtrs {
    const float* Wi[4];
    const float* Wh[4];
    const float* bi[4];
    const float* bh[4];
};

#define LOG2E 1.44269504088896340736f

// Gate pre-activations PRE-SCALED: i,f,o by log2e; g by 2*log2e (folded into
// bf16 weights + biases). Shared-rcp cell algebra (r8-verified).
__device__ __forceinline__ float cell_c(float gi, float gf, float gg, float c) {
    const float ef = __builtin_amdgcn_exp2f(-gf);
    const float ei = __builtin_amdgcn_exp2f(-gi);
    const float Eg = __builtin_amdgcn_exp2f(gg);
    const float pf = 1.0f + ef, pi = 1.0f + ei;
    const float pg = Eg + 1.0f, mg = Eg - 1.0f;
    const float num = c * pi * pg + mg * pf;
    const float den = pf * pi * pg;
    return num * __builtin_amdgcn_rcpf(den);
}
__device__ __forceinline__ float cell_h(float go, float c) {
    const float Ec = __builtin_amdgcn_exp2f(c * (2.0f * LOG2E));
    const float eo = __builtin_amdgcn_exp2f(-go);
    const float num = Ec - 1.0f;
    const float den = (1.0f + eo) * (Ec + 1.0f);
    return num * __builtin_amdgcn_rcpf(den);
}

// Half-swap within each 16-lane DPP row: lane i <-> lane i^8 (row_ror:8).
__device__ __forceinline__ float dpp_halfswap(float x) {
    int i = __float_as_int(x);
    int r = __builtin_amdgcn_update_dpp(i, i, 0x128 /*row_ror:8*/, 0xF, 0xF, false);
    return __int_as_float(r);
}

// lgkm-only barrier (r9): drains LDS ops (RAW/WAR across the barrier) but
// keeps global x-prefetch loads in flight.
__device__ __forceinline__ void phase_barrier() {
    asm volatile("s_waitcnt lgkmcnt(0)" ::: "memory");
    __builtin_amdgcn_s_barrier();
    asm volatile("" ::: "memory");
}

// Fused 4-layer LSTM, layer-pipelined across 16 waves (r4-r8 verified base).
// Grid 256 blocks = batch tiles of 8 (MFMA N=16 cols 8..15 pad; pad lanes
// repurposed via DPP half-swap: 2 REAL cells/lane). Block 1024 thr = 16 waves;
// wave w: layer l=w>>2, unit-quarter uq=w&3. SIMD = w%4 = uq -> each SIMD
// hosts waves of ALL FOUR layers.
//
// r11 vs r8: EVEN/ODD LAYER STAGGER. r8's counters showed phase time =
// MFMA-busy + VALU-busy (pipes alternate under barrier lockstep: all waves
// MFMA together, then all do trans together). Split each phase into two
// half-phases (2 lgkm barriers):
//   even layers (0,2): half A = {ds_read, MFMA -> acc}; half B = {cell, h-write}
//   odd  layers (1,3): half A = {cell of HELD acc, h-write}; half B = {ds_read,
//                      MFMA -> held acc}
// -> every half-phase: 2 waves/SIMD on MFMA pipe || 2 waves on VALU (sum->max).
// Skews: t0=p, t1=p-1, t2=p-3, t3=p-4 (518 phases). Writes -> buf[p&1];
// reads <- buf[(p-1)&1] EXCEPT odd own-h <- buf[p&1] (written 1 barrier
// earlier, same phase). Hazards: every value's last read is <=1 phase after
// its write; next overwrite 2 phases later, >=1 barrier between. s_setprio(1)
// around MFMA clusters (T5: pays once role-split exists).
__global__ __launch_bounds__(1024, 4)
void lstm_fused(const float* __restrict__ x0, float* __restrict__ last_out, WPtrs wp)
{
    const int tile = blockIdx.x;
    const int tid  = threadIdx.x;
    const int w    = tid >> 6;
    const int lane = tid & 63;
    const int l15  = lane & 15;
    const int l4   = lane >> 4;
    const int l    = w >> 2;
    const int uq   = w & 3;
    const bool hiH = (l15 >= 8);
    const int  col = l15 & 7;

    // [buf][layer][laneIdx][uq 0..3 + 2 pad] ; 24 KB ; pad cols never written
    __shared__ uint2 lds_h[2][4][64][6];
    for (int i = tid; i < 2 * 4 * 64 * 6; i += 1024)
        ((uint2*)lds_h)[i] = make_uint2(0u, 0u);

    const float* Wi = wp.Wi[l];
    const float* Wh = wp.Wh[l];
    const float gs[4] = {LOG2E, LOG2E, 2.0f * LOG2E, LOG2E};

    // ---- weight A-fragments (HW-verified lane map) ----
    bf16x8 whA[4][2];
    bf16x8 wiA[4][2];
#pragma unroll
    for (int G = 0; G < 4; ++G) {
        const float sc = gs[G];
        const int row = G * 64 + 16 * uq + l15;
        const float* r = Wh + (size_t)row * 64;
#pragma unroll
        for (int s = 0; s < 2; ++s) {
            f32x4 a = *(const f32x4*)(r + 32 * s + 4 * l4);
            f32x4 b = *(const f32x4*)(r + 32 * s + 4 * l4 + 16);
            bf16x8 f;
            f[0] = (bf16_t)(a[0] * sc); f[1] = (bf16_t)(a[1] * sc);
            f[2] = (bf16_t)(a[2] * sc); f[3] = (bf16_t)(a[3] * sc);
            f[4] = (bf16_t)(b[0] * sc); f[5] = (bf16_t)(b[1] * sc);
            f[6] = (bf16_t)(b[2] * sc); f[7] = (bf16_t)(b[3] * sc);
            whA[G][s] = f;
        }
        if (l == 0) {
            const float* ri = Wi + (size_t)row * 18;     // K=18 padded to 32
            const int k0 = 4 * l4;
            bf16x8 f;
            f[0] = (bf16_t)(ri[k0 + 0] * sc); f[1] = (bf16_t)(ri[k0 + 1] * sc);
            f[2] = (bf16_t)(ri[k0 + 2] * sc); f[3] = (bf16_t)(ri[k0 + 3] * sc);
            f[4] = (l4 == 0) ? (bf16_t)(ri[16] * sc) : (bf16_t)0.0f;
            f[5] = (l4 == 0) ? (bf16_t)(ri[17] * sc) : (bf16_t)0.0f;
            f[6] = (bf16_t)0.0f; f[7] = (bf16_t)0.0f;
            wiA[G][0] = f;
            wiA[G][1] = f;   // placeholder; [2][1]/[3][1] alias the x buffers
        } else {
            const float* ri = Wi + (size_t)row * 64;
#pragma unroll
            for (int s = 0; s < 2; ++s) {
                f32x4 a = *(const f32x4*)(ri + 32 * s + 4 * l4);
                f32x4 b = *(const f32x4*)(ri + 32 * s + 4 * l4 + 16);
                bf16x8 f;
                f[0] = (bf16_t)(a[0] * sc); f[1] = (bf16_t)(a[1] * sc);
                f[2] = (bf16_t)(a[2] * sc); f[3] = (bf16_t)(a[3] * sc);
                f[4] = (bf16_t)(b[0] * sc); f[5] = (bf16_t)(b[1] * sc);
                f[6] = (bf16_t)(b[2] * sc); f[7] = (bf16_t)(b[3] * sc);
                wiA[G][s] = f;
            }
        }
    }

    // ---- bias: ONLY the 8 post-swap scalars this lane consumes ----
    float biasA[4], biasB[4];
#pragma unroll
    for (int G = 0; G < 4; ++G) {
        const int rb = G * 64 + 16 * uq + 4 * l4 + (hiH ? 2 : 0);
        biasA[G] = (wp.bi[l][rb]     + wp.bh[l][rb])     * gs[G];
        biasB[G] = (wp.bi[l][rb + 1] + wp.bh[l][rb + 1]) * gs[G];
    }

    // ---- x prefetch (layer-0 waves), depth 2, aliased onto dead wiA slots ----
    bf16x8& xfA = wiA[2][1];
    bf16x8& xfB = wiA[3][1];
    const float* xrow = x0 + (size_t)(tile * 8 + (hiH ? 7 : col)) * (512 * 18);
    auto loadx = [&](int t, bf16x8& dst) {
        const float* xr = xrow + t * 18;
        const int k0 = 4 * l4;
        bf16x8 f;
        f[0] = (bf16_t)xr[k0 + 0]; f[1] = (bf16_t)xr[k0 + 1];
        f[2] = (bf16_t)xr[k0 + 2]; f[3] = (bf16_t)xr[k0 + 3];
        f[4] = (l4 == 0) ? (bf16_t)xr[16] : (bf16_t)0.0f;
        f[5] = (l4 == 0) ? (bf16_t)xr[17] : (bf16_t)0.0f;
        f[6] = (bf16_t)0.0f; f[7] = (bf16_t)0.0f;
        dst = f;
    };
    if (l == 0) { loadx(0, xfA); loadx(1, xfB); }

    float c0 = 0.0f, c1 = 0.0f;             // 2 real cells/lane

    // skew per layer; even/odd role
    const int  sk    = (l == 0) ? 0 : (l == 1) ? 1 : (l == 2) ? 3 : 4;
    const bool evenL = ((l & 1) == 0);

    // ONE acc for both parities: even def(half A)->use(half B) same phase;
    // odd use(half A, from previous half B)->def(half B). Single storage.
    f32x4 acc[4];

    __syncthreads();

    auto lds_frags = [&](int bi_, int ll_, Frag& f0, Frag& f1) {
        uint4 q0 = *(const uint4*)&lds_h[bi_][ll_][lane][0];
        uint4 q1 = *(const uint4*)&lds_h[bi_][ll_][lane][2];
        f0.u[0] = q0.x; f0.u[1] = q0.y; f0.u[2] = q0.z; f0.u[3] = q0.w;
        f1.u[0] = q1.x; f1.u[1] = q1.y; f1.u[2] = q1.z; f1.u[3] = q1.w;
    };

    // MFMA for even layers: inputs all from buf[br]; l0 input = xf.
    auto mfma_even = [&](int br, bf16x8& xf, int tA) {
        const f32x4 z4 = {0.0f, 0.0f, 0.0f, 0.0f};
        __builtin_amdgcn_s_setprio(1);
        if (l == 0) {
#pragma unroll
            for (int G = 0; G < 4; ++G)
                acc[G] = __builtin_amdgcn_mfma_f32_16x16x32_bf16(wiA[G][0], xf, z4, 0, 0, 0);
        } else {
            Frag b0, b1; lds_frags(br, l - 1, b0, b1);
#pragma unroll
            for (int G = 0; G < 4; ++G)
                acc[G] = __builtin_amdgcn_mfma_f32_16x16x32_bf16(wiA[G][0], b0.v, z4, 0, 0, 0);
#pragma unroll
            for (int G = 0; G < 4; ++G)
                acc[G] = __builtin_amdgcn_mfma_f32_16x16x32_bf16(wiA[G][1], b1.v, acc[G], 0, 0, 0);
        }
        Frag h0, h1; lds_frags(br, l, h0, h1);       // own h_{t-1}
#pragma unroll
        for (int G = 0; G < 4; ++G)
            acc[G] = __builtin_amdgcn_mfma_f32_16x16x32_bf16(whA[G][0], h0.v, acc[G], 0, 0, 0);
#pragma unroll
        for (int G = 0; G < 4; ++G)
            acc[G] = __builtin_amdgcn_mfma_f32_16x16x32_bf16(whA[G][1], h1.v, acc[G], 0, 0, 0);
        __builtin_amdgcn_s_setprio(0);
        if (l == 0) loadx((tA + 2) & 511, xf);       // prefetch 2 phases ahead
    };

    // MFMA for odd layers: input h^{l-1} from buf[br]; OWN h from buf[bw]
    // (written by own layer group in half A of THIS phase, 1 barrier ago).
    auto mfma_odd = [&](int br, int bw) {
        const f32x4 z4 = {0.0f, 0.0f, 0.0f, 0.0f};
        __builtin_amdgcn_s_setprio(1);
        Frag b0, b1; lds_frags(br, l - 1, b0, b1);
#pragma unroll
        for (int G = 0; G < 4; ++G)
            acc[G] = __builtin_amdgcn_mfma_f32_16x16x32_bf16(wiA[G][0], b0.v, z4, 0, 0, 0);
#pragma unroll
        for (int G = 0; G < 4; ++G)
            acc[G] = __builtin_amdgcn_mfma_f32_16x16x32_bf16(wiA[G][1], b1.v, acc[G], 0, 0, 0);
        Frag h0, h1; lds_frags(bw, l, h0, h1);       // own h_{t-1} (this phase!)
#pragma unroll
        for (int G = 0; G < 4; ++G)
            acc[G] = __builtin_amdgcn_mfma_f32_16x16x32_bf16(whA[G][0], h0.v, acc[G], 0, 0, 0);
#pragma unroll
        for (int G = 0; G < 4; ++G)
            acc[G] = __builtin_amdgcn_mfma_f32_16x16x32_bf16(whA[G][1], h1.v, acc[G], 0, 0, 0);
        __builtin_amdgcn_s_setprio(0);
    };

    // Cell update + h write (both parities). tt = this h's timestep.
    auto do_cell = [&](int bw, int tt) {
        float g0[4], g1[4];
#pragma unroll
        for (int G = 0; G < 4; ++G) {
            const float s2 = dpp_halfswap(acc[G][2]);
            const float s3 = dpp_halfswap(acc[G][3]);
            g0[G] = (hiH ? s2 : acc[G][0]) + biasA[G];
            g1[G] = (hiH ? s3 : acc[G][1]) + biasB[G];
        }
        const float cA = cell_c(g0[0], g0[1], g0[2], c0);
        const float cB = cell_c(g1[0], g1[1], g1[2], c1);
        c0 = cA; c1 = cB;
        const float hA = cell_h(g0[3], cA);
        const float hB = cell_h(g1[3], cB);
        union { uint32_t u; bf16_t b[2]; } pk;
        pk.b[0] = (bf16_t)hA; pk.b[1] = (bf16_t)hB;
        uint32_t* slot = (uint32_t*)&lds_h[bw][l][16 * l4 + col][uq];
        slot[hiH ? 1 : 0] = pk.u;
        if (l == 3 && tt == 511) {
            float* o = last_out + ((size_t)(tile * 8 + col)) * 64
                       + 16 * uq + 4 * l4 + (hiH ? 2 : 0);
            *(float2*)o = make_float2(hA, hB);
        }
    };

    // br/bw are LITERALS from the unrolled call sites (bw = p&1, br = bw^1).
    auto phase = [&](int p, int br, int bw, bf16x8& xf) {
        const int tA = p - sk;          // even: MFMA+cell target ; odd: MFMA target
        const int tC = p - 1 - sk;      // odd: cell target (held acc from p-1)
        // ---- half A: even MFMA || odd cell ----
        if (evenL) {
            if ((unsigned)tA < 512u) mfma_even(br, xf, tA);
        } else {
            if ((unsigned)tC < 512u) do_cell(bw, tC);
        }
        phase_barrier();
        // ---- half B: even cell || odd MFMA ----
        if (evenL) {
            if ((unsigned)tA < 512u) do_cell(bw, tA);
        } else {
            if ((unsigned)tA < 512u) mfma_odd(br, bw);
        }
        phase_barrier();
    };

    // l3's last cell: tC=511 at p=516 -> loop to 517 (guards idle the tail).
    for (int p = 0; p < 518; p += 2) {
        phase(p,     1, 0, xfA);      // even p: read buf1, write buf0
        phase(p + 1, 0, 1, xfB);      // odd  p: read buf0, write buf1
    }
}

// out = relu(last @ W1^T + b1) @ W2^T + b2   (f32, tiny)
__global__ __launch_bounds__(256)
void mlp_head(const float* __restrict__ last,
              const float* __restrict__ W1, const float* __restrict__ b1,
              const float* __restrict__ W2, const float* __restrict__ b2,
              float* __restrict__ out)
{
    __shared__ float sW1[128 * 64];
    __shared__ float sb1[128];
    __shared__ float sW2[3 * 128];
    __shared__ float sb2[4];
    const int tid = threadIdx.x;
    for (int i = tid; i < 128 * 64; i += 256) sW1[i] = W1[i];
    for (int i = tid; i < 128; i += 256) sb1[i] = b1[i];
    for (int i = tid; i < 3 * 128; i += 256) sW2[i] = W2[i];
    if (tid < 3) sb2[tid] = b2[tid];
    __syncthreads();

    const int b = blockIdx.x * 256 + tid;
    const float* lb = last + (size_t)b * 64;
    float xv[64];
#pragma unroll
    for (int k = 0; k < 64; k += 4) {
        f32x4 v = *(const f32x4*)(lb + k);
        xv[k] = v[0]; xv[k + 1] = v[1]; xv[k + 2] = v[2]; xv[k + 3] = v[3];
    }
    float o0 = sb2[0], o1 = sb2[1], o2 = sb2[2];
    for (int j = 0; j < 128; ++j) {
        float a = sb1[j];
        const float* wr = &sW1[j * 64];
#pragma unroll
        for (int k = 0; k < 64; k += 4) {
            f32x4 wv = *(const f32x4*)(wr + k);
            a += xv[k] * wv[0] + xv[k + 1] * wv[1] + xv[k + 2] * wv[2] + xv[k + 3] * wv[3];
        }
        a = fmaxf(a, 0.0f);
        o0 += a * sW2[0 * 128 + j];
        o1 += a * sW2[1 * 128 + j];
        o2 += a * sW2[2 * 128 + j];
    }
    out[(size_t)b * 3 + 0] = o0;
    out[(size_t)b * 3 + 1] = o1;
    out[(size_t)b * 3 + 2] = o2;
}

extern "C" void kernel_launch(void* const* d_in, const int* in_sizes, int n_in,
                              void* d_out, int out_size, void* d_ws, size_t ws_size,
                              hipStream_t stream)
{
    (void)in_sizes; (void)n_in; (void)out_size; (void)ws_size;

    const float* x = (const float*)d_in[0];
    WPtrs wp;
    for (int l = 0; l < 4; ++l) {
        wp.Wi[l] = (const float*)d_in[1 + 4 * l + 0];
        wp.Wh[l] = (const float*)d_in[1 + 4 * l + 1];
        wp.bi[l] = (const float*)d_in[1 + 4 * l + 2];
        wp.bh[l] = (const float*)d_in[1 + 4 * l + 3];
    }
    const float* W1 = (const float*)d_in[17];
    const float* b1 = (const float*)d_in[18];
    const float* W2 = (const float*)d_in[19];
    const float* b2 = (const float*)d_in[20];

    float* last = (float*)d_ws;                 // 2048*64 f32 = 512 KiB

    lstm_fused<<<dim3(256), dim3(1024), 0, stream>>>(x, last, wp);
    mlp_head<<<dim3(8), dim3(256), 0, stream>>>(last, W1, b1, W2, b2, (float*)d_out);
}

// Round 13
// 622.804 us; speedup vs baseline: 6.4040x; 1.0604x over previous
//
#include <hip/hip_runtime.h>
#include <stdint.h>

typedef __bf16 bf16_t;
typedef __bf16 bf16x8 __attribute__((ext_vector_type(8)));
typedef float  f32x4  __attribute__((ext_vector_type(4)));

union Frag { uint32_t u[4]; bf16x8 v; };

struct WPtrs {
    const float* Wi[4];
    const float* Wh[4];
    const float* bi[4];
    const float* bh[4];
};

#define LOG2E 1.44269504088896340736f

// Gate pre-activations PRE-SCALED: i,f,o by log2e; g by 2*log2e (folded into
// bf16 weights + biases). Shared-rcp cell algebra (r8-verified).
__device__ __forceinline__ float cell_c(float gi, float gf, float gg, float c) {
    const float ef = __builtin_amdgcn_exp2f(-gf);
    const float ei = __builtin_amdgcn_exp2f(-gi);
    const float Eg = __builtin_amdgcn_exp2f(gg);
    const float pf = 1.0f + ef, pi = 1.0f + ei;
    const float pg = Eg + 1.0f, mg = Eg - 1.0f;
    const float num = c * pi * pg + mg * pf;
    const float den = pf * pi * pg;
    return num * __builtin_amdgcn_rcpf(den);
}
__device__ __forceinline__ float cell_h(float go, float c) {
    const float Ec = __builtin_amdgcn_exp2f(c * (2.0f * LOG2E));
    const float eo = __builtin_amdgcn_exp2f(-go);
    const float num = Ec - 1.0f;
    const float den = (1.0f + eo) * (Ec + 1.0f);
    return num * __builtin_amdgcn_rcpf(den);
}

// Half-swap within each 16-lane DPP row: lane i <-> lane i^8 (row_ror:8).
__device__ __forceinline__ float dpp_halfswap(float x) {
    int i = __float_as_int(x);
    int r = __builtin_amdgcn_update_dpp(i, i, 0x128 /*row_ror:8*/, 0xF, 0xF, false);
    return __int_as_float(r);
}

// r13 = r12 + ONE-LINE FIX: upstream h_t lives in buf t%3 (=bw), written at
// upstream's step t. r12 read lds_h[br][l-1] (br=(t+2)%3), i.e. STALE h_{t-1}
// -> deterministic absmax 8.8e-3. Own h_{t-1} correctly stays at br.
//
// Protocol (done[l] = sum of per-wave step completions; bump AFTER lgkmcnt(0)
// drain of h-writes):
//   before step t: (a) done[l]   >= 4t
//                  (b) done[l-1] >= 4(t+1)   [l>0]
//                  (c) done[l+1] >= 4(t-2)   [l<3]
// PROVEN (r12 post-mortem): the 4-wave sum counter enforces intra-layer
// LOCKSTEP (no wave starts t+1 until all siblings complete t; induction on
// the first-starter's poll). Consequences:
//   - (b) => upstream h_t written+drained before my read of buf t%3.
//   - downstream executes in [t-2, t-1] during my step t (its (b) caps it at
//     t-1; my (c) floors it) => it reads bufs (t-1)%3/(t-2)%3, never t%3.
//   - upstream can't overwrite buf t%3 (its step t+3) until its (c) sees
//     done[l] >= 4(t+1), i.e. my layer completed t.
// Deadlock-free: deps form a DAG cascading from layer 0; exited layers leave
// final counter values that satisfy all residual conditions.
// Stagger: one-time ~1Kcyc startup sleep for odd layers de-aligns MFMA vs
// trans sections per SIMD (SIMD id = uq hosts all 4 layers); ring depth 3
// provides the slack so the offset persists.
__global__ __launch_bounds__(1024, 4)
void lstm_fused(const float* __restrict__ x0, float* __restrict__ last_out, WPtrs wp)
{
    const int tile = blockIdx.x;
    const int tid  = threadIdx.x;
    const int w    = tid >> 6;
    const int lane = tid & 63;
    const int l15  = lane & 15;
    const int l4   = lane >> 4;
    const int l    = w >> 2;
    const int uq   = w & 3;                 // SIMD id: each SIMD gets l=0..3
    const bool hiH = (l15 >= 8);
    const int  col = l15 & 7;

    // ring depth 3: [buf][layer][laneIdx][uq 0..3 + 2 pad] ; 36 KB
    __shared__ uint2 lds_h[3][4][64][6];
    __shared__ int   done4[4];
    for (int i = tid; i < 3 * 4 * 64 * 6; i += 1024)
        ((uint2*)lds_h)[i] = make_uint2(0u, 0u);
    if (tid < 4) done4[tid] = 0;

    const float* Wi = wp.Wi[l];
    const float* Wh = wp.Wh[l];
    const float gs[4] = {LOG2E, LOG2E, 2.0f * LOG2E, LOG2E};

    // ---- weight A-fragments (HW-verified lane map) ----
    bf16x8 whA[4][2];
    bf16x8 wiA[4][2];
#pragma unroll
    for (int G = 0; G < 4; ++G) {
        const float sc = gs[G];
        const int row = G * 64 + 16 * uq + l15;
        const float* r = Wh + (size_t)row * 64;
#pragma unroll
        for (int s = 0; s < 2; ++s) {
            f32x4 a = *(const f32x4*)(r + 32 * s + 4 * l4);
            f32x4 b = *(const f32x4*)(r + 32 * s + 4 * l4 + 16);
            bf16x8 f;
            f[0] = (bf16_t)(a[0] * sc); f[1] = (bf16_t)(a[1] * sc);
            f[2] = (bf16_t)(a[2] * sc); f[3] = (bf16_t)(a[3] * sc);
            f[4] = (bf16_t)(b[0] * sc); f[5] = (bf16_t)(b[1] * sc);
            f[6] = (bf16_t)(b[2] * sc); f[7] = (bf16_t)(b[3] * sc);
            whA[G][s] = f;
        }
        if (l == 0) {
            const float* ri = Wi + (size_t)row * 18;     // K=18 padded to 32
            const int k0 = 4 * l4;
            bf16x8 f;
            f[0] = (bf16_t)(ri[k0 + 0] * sc); f[1] = (bf16_t)(ri[k0 + 1] * sc);
            f[2] = (bf16_t)(ri[k0 + 2] * sc); f[3] = (bf16_t)(ri[k0 + 3] * sc);
            f[4] = (l4 == 0) ? (bf16_t)(ri[16] * sc) : (bf16_t)0.0f;
            f[5] = (l4 == 0) ? (bf16_t)(ri[17] * sc) : (bf16_t)0.0f;
            f[6] = (bf16_t)0.0f; f[7] = (bf16_t)0.0f;
            wiA[G][0] = f;
            wiA[G][1] = f;   // placeholder; [2][1]/[3][1] alias the x buffers
        } else {
            const float* ri = Wi + (size_t)row * 64;
#pragma unroll
            for (int s = 0; s < 2; ++s) {
                f32x4 a = *(const f32x4*)(ri + 32 * s + 4 * l4);
                f32x4 b = *(const f32x4*)(ri + 32 * s + 4 * l4 + 16);
                bf16x8 f;
                f[0] = (bf16_t)(a[0] * sc); f[1] = (bf16_t)(a[1] * sc);
                f[2] = (bf16_t)(a[2] * sc); f[3] = (bf16_t)(a[3] * sc);
                f[4] = (bf16_t)(b[0] * sc); f[5] = (bf16_t)(b[1] * sc);
                f[6] = (bf16_t)(b[2] * sc); f[7] = (bf16_t)(b[3] * sc);
                wiA[G][s] = f;
            }
        }
    }

    // ---- bias: ONLY the 8 post-swap scalars this lane consumes ----
    float biasA[4], biasB[4];
#pragma unroll
    for (int G = 0; G < 4; ++G) {
        const int rb = G * 64 + 16 * uq + 4 * l4 + (hiH ? 2 : 0);
        biasA[G] = (wp.bi[l][rb]     + wp.bh[l][rb])     * gs[G];
        biasB[G] = (wp.bi[l][rb + 1] + wp.bh[l][rb + 1]) * gs[G];
    }

    // ---- x prefetch (layer-0 waves), depth 2, aliased onto dead wiA slots ----
    bf16x8& xfA = wiA[2][1];
    bf16x8& xfB = wiA[3][1];
    const float* xrow = x0 + (size_t)(tile * 8 + (hiH ? 7 : col)) * (512 * 18);
    auto loadx = [&](int t, bf16x8& dst) {
        const float* xr = xrow + t * 18;
        const int k0 = 4 * l4;
        bf16x8 f;
        f[0] = (bf16_t)xr[k0 + 0]; f[1] = (bf16_t)xr[k0 + 1];
        f[2] = (bf16_t)xr[k0 + 2]; f[3] = (bf16_t)xr[k0 + 3];
        f[4] = (l4 == 0) ? (bf16_t)xr[16] : (bf16_t)0.0f;
        f[5] = (l4 == 0) ? (bf16_t)xr[17] : (bf16_t)0.0f;
        f[6] = (bf16_t)0.0f; f[7] = (bf16_t)0.0f;
        dst = f;
    };
    if (l == 0) { loadx(0, xfA); loadx(1, xfB); }

    float c0 = 0.0f, c1 = 0.0f;             // 2 real cells/lane

    __syncthreads();    // ONE barrier total: after init

    volatile int* dp = done4;

    // br/bw are LITERALS from the 6-unrolled call sites:
    //   bw = t%3 (own h_t write AND upstream h_t read), br = (t+2)%3 (own h_{t-1}).
    auto step = [&](int t, int br, int bw, bf16x8& xf) {
        // ---- flag poll (wave-uniform values; LDS broadcast reads) ----
        {
            const int needA = 4 * t, needU = 4 * (t + 1), needD = 4 * (t - 2);
            for (;;) {
                bool ok = (dp[l] >= needA);
                if (l > 0) ok = ok && (dp[l - 1] >= needU);
                if (l < 3) ok = ok && (dp[l + 1] >= needD);
                if (ok) break;
                __builtin_amdgcn_s_sleep(1);
            }
            asm volatile("" ::: "memory");   // no LDS reads hoisted above poll
        }

        const f32x4 z4 = {0.0f, 0.0f, 0.0f, 0.0f};
        f32x4 acc[4];

        __builtin_amdgcn_s_setprio(1);
        if (l == 0) {
#pragma unroll
            for (int G = 0; G < 4; ++G)
                acc[G] = __builtin_amdgcn_mfma_f32_16x16x32_bf16(wiA[G][0], xf, z4, 0, 0, 0);
            loadx((t + 2) & 511, xf);        // prefetch 2 steps ahead
        } else {
            // FIX (r13): upstream h_t is in buf bw = t%3 (upstream wrote it at
            // its own step t). r12 wrongly read br (= stale h_{t-1}).
            Frag b0, b1;
            uint4 q0 = *(const uint4*)&lds_h[bw][l - 1][lane][0];
            uint4 q1 = *(const uint4*)&lds_h[bw][l - 1][lane][2];
            b0.u[0] = q0.x; b0.u[1] = q0.y; b0.u[2] = q0.z; b0.u[3] = q0.w;
            b1.u[0] = q1.x; b1.u[1] = q1.y; b1.u[2] = q1.z; b1.u[3] = q1.w;
#pragma unroll
            for (int G = 0; G < 4; ++G)
                acc[G] = __builtin_amdgcn_mfma_f32_16x16x32_bf16(wiA[G][0], b0.v, z4, 0, 0, 0);
#pragma unroll
            for (int G = 0; G < 4; ++G)
                acc[G] = __builtin_amdgcn_mfma_f32_16x16x32_bf16(wiA[G][1], b1.v, acc[G], 0, 0, 0);
        }
        {
            Frag h0, h1;
            uint4 q0 = *(const uint4*)&lds_h[br][l][lane][0];
            uint4 q1 = *(const uint4*)&lds_h[br][l][lane][2];
            h0.u[0] = q0.x; h0.u[1] = q0.y; h0.u[2] = q0.z; h0.u[3] = q0.w;
            h1.u[0] = q1.x; h1.u[1] = q1.y; h1.u[2] = q1.z; h1.u[3] = q1.w;
#pragma unroll
            for (int G = 0; G < 4; ++G)
                acc[G] = __builtin_amdgcn_mfma_f32_16x16x32_bf16(whA[G][0], h0.v, acc[G], 0, 0, 0);
#pragma unroll
            for (int G = 0; G < 4; ++G)
                acc[G] = __builtin_amdgcn_mfma_f32_16x16x32_bf16(whA[G][1], h1.v, acc[G], 0, 0, 0);
        }
        __builtin_amdgcn_s_setprio(0);

        // ---- DPP half-swap + bias + cells (r8-identical math) ----
        float g0[4], g1[4];
#pragma unroll
        for (int G = 0; G < 4; ++G) {
            const float s2 = dpp_halfswap(acc[G][2]);
            const float s3 = dpp_halfswap(acc[G][3]);
            g0[G] = (hiH ? s2 : acc[G][0]) + biasA[G];
            g1[G] = (hiH ? s3 : acc[G][1]) + biasB[G];
        }
        const float cA = cell_c(g0[0], g0[1], g0[2], c0);
        const float cB = cell_c(g1[0], g1[1], g1[2], c1);
        c0 = cA; c1 = cB;
        const float hA = cell_h(g0[3], cA);
        const float hB = cell_h(g1[3], cB);

        union { uint32_t u; bf16_t b[2]; } pk;
        pk.b[0] = (bf16_t)hA; pk.b[1] = (bf16_t)hB;
        uint32_t* slot = (uint32_t*)&lds_h[bw][l][16 * l4 + col][uq];
        slot[hiH ? 1 : 0] = pk.u;

        if (l == 3 && t == 511) {
            float* o = last_out + ((size_t)(tile * 8 + col)) * 64
                       + 16 * uq + 4 * l4 + (hiH ? 2 : 0);
            *(float2*)o = make_float2(hA, hB);
        }

        // ---- publish: drain h-writes, then bump counter ----
        asm volatile("s_waitcnt lgkmcnt(0)" ::: "memory");
        if (lane == 0) atomicAdd(&done4[l], 1);
        asm volatile("" ::: "memory");
    };

    // One-time ~1Kcyc stagger for odd layers: persists through the dep cascade
    // (ring depth 3 gives the slack), de-aligning MFMA vs trans sections.
    if (l & 1) { __builtin_amdgcn_s_sleep(8); __builtin_amdgcn_s_sleep(8); }

    // 6-unroll: xf parity (2) x ring (3). 512 = 85*6 + 2.
    for (int t = 0; t < 510; t += 6) {
        step(t + 0, 2, 0, xfA);
        step(t + 1, 0, 1, xfB);
        step(t + 2, 1, 2, xfA);
        step(t + 3, 2, 0, xfB);
        step(t + 4, 0, 1, xfA);
        step(t + 5, 1, 2, xfB);
    }
    step(510, 2, 0, xfA);
    step(511, 0, 1, xfB);
}

// out = relu(last @ W1^T + b1) @ W2^T + b2   (f32, tiny)
__global__ __launch_bounds__(256)
void mlp_head(const float* __restrict__ last,
              const float* __restrict__ W1, const float* __restrict__ b1,
              const float* __restrict__ W2, const float* __restrict__ b2,
              float* __restrict__ out)
{
    __shared__ float sW1[128 * 64];
    __shared__ float sb1[128];
    __shared__ float sW2[3 * 128];
    __shared__ float sb2[4];
    const int tid = threadIdx.x;
    for (int i = tid; i < 128 * 64; i += 256) sW1[i] = W1[i];
    for (int i = tid; i < 128; i += 256) sb1[i] = b1[i];
    for (int i = tid; i < 3 * 128; i += 256) sW2[i] = W2[i];
    if (tid < 3) sb2[tid] = b2[tid];
    __syncthreads();

    const int b = blockIdx.x * 256 + tid;
    const float* lb = last + (size_t)b * 64;
    float xv[64];
#pragma unroll
    for (int k = 0; k < 64; k += 4) {
        f32x4 v = *(const f32x4*)(lb + k);
        xv[k] = v[0]; xv[k + 1] = v[1]; xv[k + 2] = v[2]; xv[k + 3] = v[3];
    }
    float o0 = sb2[0], o1 = sb2[1], o2 = sb2[2];
    for (int j = 0; j < 128; ++j) {
        float a = sb1[j];
        const float* wr = &sW1[j * 64];
#pragma unroll
        for (int k = 0; k < 64; k += 4) {
            f32x4 wv = *(const f32x4*)(wr + k);
            a += xv[k] * wv[0] + xv[k + 1] * wv[1] + xv[k + 2] * wv[2] + xv[k + 3] * wv[3];
        }
        a = fmaxf(a, 0.0f);
        o0 += a * sW2[0 * 128 + j];
        o1 += a * sW2[1 * 128 + j];
        o2 += a * sW2[2 * 128 + j];
    }
    out[(size_t)b * 3 + 0] = o0;
    out[(size_t)b * 3 + 1] = o1;
    out[(size_t)b * 3 + 2] = o2;
}

extern "C" void kernel_launch(void* const* d_in, const int* in_sizes, int n_in,
                              void* d_out, int out_size, void* d_ws, size_t ws_size,
                              hipStream_t stream)
{
    (void)in_sizes; (void)n_in; (void)out_size; (void)ws_size;

    const float* x = (const float*)d_in[0];
    WPtrs wp;
    for (int l = 0; l < 4; ++l) {
        wp.Wi[l] = (const float*)d_in[1 + 4 * l + 0];
        wp.Wh[l] = (const float*)d_in[1 + 4 * l + 1];
        wp.bi[l] = (const float*)d_in[1 + 4 * l + 2];
        wp.bh[l] = (const float*)d_in[1 + 4 * l + 3];
    }
    const float* W1 = (const float*)d_in[17];
    const float* b1 = (const float*)d_in[18];
    const float* W2 = (const float*)d_in[19];
    const float* b2 = (const float*)d_in[20];

    float* last = (float*)d_ws;                 // 2048*64 f32 = 512 KiB

    lstm_fused<<<dim3(256), dim3(1024), 0, stream>>>(x, last, wp);
    mlp_head<<<dim3(8), dim3(256), 0, stream>>>(last, W1, b1, W2, b2, (float*)d_out);
}

// Round 14
// 581.466 us; speedup vs baseline: 6.8593x; 1.0711x over previous
//
#include <hip/hip_runtime.h>
#include <stdint.h>

typedef __bf16 bf16_t;
typedef __bf16 bf16x8 __attribute__((ext_vector_type(8)));
typedef float  f32x4  __attribute__((ext_vector_type(4)));

union Frag { uint32_t u[4]; bf16x8 v; };

struct WPtrs {
    const float* Wi[4];
    const float* Wh[4];
    const float* bi[4];
    const float* bh[4];
};

#define LOG2E 1.44269504088896340736f

// Gate pre-activations arrive PRE-SCALED: i,f,o by log2e; g by 2*log2e
// (folded into bf16 weight fragments + biases at build time).
// Shared-rcp cell algebra (r8): one rcp per c-update, one per h-update.
//   c' = sigma(f)*c + sigma(i)*tanh(g)
//      = [c*(1+ei)*(Eg+1) + (Eg-1)*(1+ef)] / [(1+ef)*(1+ei)*(Eg+1)]
//   h  = sigma(o)*tanh(c') = (Ec-1) / [(1+eo)*(Ec+1)]
__device__ __forceinline__ float cell_c(float gi, float gf, float gg, float c) {
    const float ef = __builtin_amdgcn_exp2f(-gf);
    const float ei = __builtin_amdgcn_exp2f(-gi);
    const float Eg = __builtin_amdgcn_exp2f(gg);
    const float pf = 1.0f + ef, pi = 1.0f + ei;
    const float pg = Eg + 1.0f, mg = Eg - 1.0f;
    const float num = c * pi * pg + mg * pf;
    const float den = pf * pi * pg;
    return num * __builtin_amdgcn_rcpf(den);
}
__device__ __forceinline__ float cell_h(float go, float c) {
    const float Ec = __builtin_amdgcn_exp2f(c * (2.0f * LOG2E));
    const float eo = __builtin_amdgcn_exp2f(-go);
    const float num = Ec - 1.0f;
    const float den = (1.0f + eo) * (Ec + 1.0f);
    return num * __builtin_amdgcn_rcpf(den);
}

// Half-swap within each 16-lane DPP row: lane i <-> lane i^8 (row_ror:8).
__device__ __forceinline__ float dpp_halfswap(float x) {
    int i = __float_as_int(x);
    int r = __builtin_amdgcn_update_dpp(i, i, 0x128 /*row_ror:8*/, 0xF, 0xF, false);
    return __int_as_float(r);
}

// r14 = EXACT restore of r8 (581 us, best measured). Rationale: three
// structural de-alignment attempts all regressed (r11 +2 barriers: 660;
// r12/r13 flag free-run: 658/622; r10 cross-block: 3930). The phase model
// phase ~= LDS-burst + MFMA-chain + VALU-chain (2780 cyc) holds; every sync
// mechanism that could overlap MFMA under VALU costs 300-500 cyc/phase
// against a ~1000-cyc prize. Pad columns are free (MFMA is not the binding
// pipe). Locking in the verified best.
//
// Fused 4-layer LSTM, layer-pipelined across 16 waves (structure HW-verified
// r4-r8). Grid 256 blocks = batch tiles of 8 (MFMA N=16, cols 8..15 pad; pad
// lanes repurposed via DPP half-swap so all 64 lanes compute 2 REAL cells).
// Block 1024 thr = 16 waves; wave w: layer l=w>>2, unit-quarter uq=w&3.
// Phase p: layer l computes t=p-l; 1 barrier/phase; lds_h double-buffered.
//  (1) lds_h [buf][layer][laneIdx][6 uint2] (48B stride, 16B-aligned):
//      B-frag = ONE ds_read_b128; 48B stride keeps banks <=2-way; br/bw are
//      literal constants -> LDS offsets fold to immediates.
//  (2) shared-rcp cell math: 14 trans/wave/phase.
//  (3) x prefetch depth 2 aliased onto dead wiA[2][1]/wiA[3][1] slots
//      (reg demand ~123 < 128 cap; no spill: WRITE_SIZE 512 KB).
__global__ __launch_bounds__(1024, 4)
void lstm_fused(const float* __restrict__ x0, float* __restrict__ last_out, WPtrs wp)
{
    const int tile = blockIdx.x;
    const int tid  = threadIdx.x;
    const int w    = tid >> 6;
    const int lane = tid & 63;
    const int l15  = lane & 15;
    const int l4   = lane >> 4;
    const int l    = w >> 2;
    const int uq   = w & 3;
    const bool hiH = (l15 >= 8);
    const int  col = l15 & 7;

    // [buf][layer][laneIdx][ut 0..3 + 2 pad] ; laneIdx = 16*l4 + col ; 24 KB
    __shared__ uint2 lds_h[2][4][64][6];

    for (int i = tid; i < 2 * 4 * 64 * 6; i += 1024)
        ((uint2*)lds_h)[i] = make_uint2(0u, 0u);

    const float* Wi = wp.Wi[l];
    const float* Wh = wp.Wh[l];

    // per-gate prescale: i,f,o -> log2e ; g -> 2*log2e
    const float gs[4] = {LOG2E, LOG2E, 2.0f * LOG2E, LOG2E};

    // ---- weight A-fragments (loop-invariant registers) ----
    // A-frag lane map (HW-verified): row = base + l15, k = 32*s + 4*l4 + j (+16 for j>=4)
    bf16x8 whA[4][2];
    bf16x8 wiA[4][2];
#pragma unroll
    for (int G = 0; G < 4; ++G) {
        const float sc = gs[G];
        const int row = G * 64 + 16 * uq + l15;
        const float* r = Wh + (size_t)row * 64;
#pragma unroll
        for (int s = 0; s < 2; ++s) {
            f32x4 a = *(const f32x4*)(r + 32 * s + 4 * l4);
            f32x4 b = *(const f32x4*)(r + 32 * s + 4 * l4 + 16);
            bf16x8 f;
            f[0] = (bf16_t)(a[0] * sc); f[1] = (bf16_t)(a[1] * sc);
            f[2] = (bf16_t)(a[2] * sc); f[3] = (bf16_t)(a[3] * sc);
            f[4] = (bf16_t)(b[0] * sc); f[5] = (bf16_t)(b[1] * sc);
            f[6] = (bf16_t)(b[2] * sc); f[7] = (bf16_t)(b[3] * sc);
            whA[G][s] = f;
        }
        if (l == 0) {
            const float* ri = Wi + (size_t)row * 18;     // K=18 padded to 32
            const int k0 = 4 * l4;
            bf16x8 f;
            f[0] = (bf16_t)(ri[k0 + 0] * sc); f[1] = (bf16_t)(ri[k0 + 1] * sc);
            f[2] = (bf16_t)(ri[k0 + 2] * sc); f[3] = (bf16_t)(ri[k0 + 3] * sc);
            f[4] = (l4 == 0) ? (bf16_t)(ri[16] * sc) : (bf16_t)0.0f;
            f[5] = (l4 == 0) ? (bf16_t)(ri[17] * sc) : (bf16_t)0.0f;
            f[6] = (bf16_t)0.0f; f[7] = (bf16_t)0.0f;
            wiA[G][0] = f;
            wiA[G][1] = f;   // placeholder; [2][1]/[3][1] become x buffers below
        } else {
            const float* ri = Wi + (size_t)row * 64;
#pragma unroll
            for (int s = 0; s < 2; ++s) {
                f32x4 a = *(const f32x4*)(ri + 32 * s + 4 * l4);
                f32x4 b = *(const f32x4*)(ri + 32 * s + 4 * l4 + 16);
                bf16x8 f;
                f[0] = (bf16_t)(a[0] * sc); f[1] = (bf16_t)(a[1] * sc);
                f[2] = (bf16_t)(a[2] * sc); f[3] = (bf16_t)(a[3] * sc);
                f[4] = (bf16_t)(b[0] * sc); f[5] = (bf16_t)(b[1] * sc);
                f[6] = (bf16_t)(b[2] * sc); f[7] = (bf16_t)(b[3] * sc);
                wiA[G][s] = f;
            }
        }
    }

    // ---- bias: ONLY the 8 post-swap scalars this lane consumes ----
    float biasA[4], biasB[4];
#pragma unroll
    for (int G = 0; G < 4; ++G) {
        const int rb = G * 64 + 16 * uq + 4 * l4 + (hiH ? 2 : 0);
        biasA[G] = (wp.bi[l][rb]     + wp.bh[l][rb])     * gs[G];
        biasB[G] = (wp.bi[l][rb + 1] + wp.bh[l][rb + 1]) * gs[G];
    }

    // ---- x prefetch (layer-0 waves), depth 2 ----
    // ALIASED onto wiA[2][1] / wiA[3][1]: dead slots for l==0, untouched by l>0.
    bf16x8& xfA = wiA[2][1];
    bf16x8& xfB = wiA[3][1];
    const int    xbatch = tile * 8 + (hiH ? 7 : col);
    const float* xrow   = x0 + (size_t)xbatch * (512 * 18);
    auto loadx = [&](int t, bf16x8& dst) {
        const float* xr = xrow + t * 18;
        const int k0 = 4 * l4;
        bf16x8 f;
        f[0] = (bf16_t)xr[k0 + 0]; f[1] = (bf16_t)xr[k0 + 1];
        f[2] = (bf16_t)xr[k0 + 2]; f[3] = (bf16_t)xr[k0 + 3];
        f[4] = (l4 == 0) ? (bf16_t)xr[16] : (bf16_t)0.0f;
        f[5] = (l4 == 0) ? (bf16_t)xr[17] : (bf16_t)0.0f;
        f[6] = (bf16_t)0.0f; f[7] = (bf16_t)0.0f;
        dst = f;
    };
    if (l == 0) { loadx(0, xfA); loadx(1, xfB); }

    float c0 = 0.0f, c1 = 0.0f;     // 2 real cells/lane

    __syncthreads();

    // br/bw arrive as LITERAL constants from the unrolled call sites.
    auto phase = [&](int p, int br, int bw, bf16x8& xf) {
        const int t = p - l;
        if (t >= 0 && t < 512) {
            const f32x4 z4 = {0.0f, 0.0f, 0.0f, 0.0f};
            f32x4 acc[4];

            // ---- x contribution (C starts at zero; bias added post-DPP) ----
            if (l == 0) {
#pragma unroll
                for (int G = 0; G < 4; ++G)
                    acc[G] = __builtin_amdgcn_mfma_f32_16x16x32_bf16(wiA[G][0], xf, z4, 0, 0, 0);
                loadx((t + 2) & 511, xf);       // prefetch 2 ahead (wrap harmless)
            } else {
                Frag b0, b1;
                {
                    uint4 q0 = *(const uint4*)&lds_h[br][l - 1][lane][0];
                    uint4 q1 = *(const uint4*)&lds_h[br][l - 1][lane][2];
                    b0.u[0] = q0.x; b0.u[1] = q0.y; b0.u[2] = q0.z; b0.u[3] = q0.w;
                    b1.u[0] = q1.x; b1.u[1] = q1.y; b1.u[2] = q1.z; b1.u[3] = q1.w;
                }
#pragma unroll
                for (int G = 0; G < 4; ++G)
                    acc[G] = __builtin_amdgcn_mfma_f32_16x16x32_bf16(wiA[G][0], b0.v, z4, 0, 0, 0);
#pragma unroll
                for (int G = 0; G < 4; ++G)
                    acc[G] = __builtin_amdgcn_mfma_f32_16x16x32_bf16(wiA[G][1], b1.v, acc[G], 0, 0, 0);
            }

            // ---- h contribution (own layer, t-1): 2 x ds_read_b128 ----
            {
                Frag h0, h1;
                uint4 q0 = *(const uint4*)&lds_h[br][l][lane][0];
                uint4 q1 = *(const uint4*)&lds_h[br][l][lane][2];
                h0.u[0] = q0.x; h0.u[1] = q0.y; h0.u[2] = q0.z; h0.u[3] = q0.w;
                h1.u[0] = q1.x; h1.u[1] = q1.y; h1.u[2] = q1.z; h1.u[3] = q1.w;
#pragma unroll
                for (int G = 0; G < 4; ++G)
                    acc[G] = __builtin_amdgcn_mfma_f32_16x16x32_bf16(whA[G][0], h0.v, acc[G], 0, 0, 0);
#pragma unroll
                for (int G = 0; G < 4; ++G)
                    acc[G] = __builtin_amdgcn_mfma_f32_16x16x32_bf16(whA[G][1], h1.v, acc[G], 0, 0, 0);
            }

            // ---- DPP half-swap: every lane gets 2 REAL cells; add bias here ----
            float g0[4], g1[4];
#pragma unroll
            for (int G = 0; G < 4; ++G) {
                const float s2 = dpp_halfswap(acc[G][2]);
                const float s3 = dpp_halfswap(acc[G][3]);
                g0[G] = (hiH ? s2 : acc[G][0]) + biasA[G];
                g1[G] = (hiH ? s3 : acc[G][1]) + biasB[G];
            }

            // ---- cell update (shared-rcp, prescaled gates) ----
            const float cA = cell_c(g0[0], g0[1], g0[2], c0);
            const float cB = cell_c(g1[0], g1[1], g1[2], c1);
            c0 = cA; c1 = cB;
            const float hA = cell_h(g0[3], cA);
            const float hB = cell_h(g1[3], cB);

            // ---- h writeback: one b32 per lane; pad laneIdx slots never written ----
            union { uint32_t u; bf16_t b[2]; } pk;
            pk.b[0] = (bf16_t)hA; pk.b[1] = (bf16_t)hB;
            uint32_t* slot = (uint32_t*)&lds_h[bw][l][16 * l4 + col][uq];
            slot[hiH ? 1 : 0] = pk.u;

            if (l == 3 && t == 511) {
                float* o = last_out + ((size_t)(tile * 8 + col)) * 64
                           + 16 * uq + 4 * l4 + (hiH ? 2 : 0);
                *(float2*)o = make_float2(hA, hB);
            }
        }
        __syncthreads();
    };

    // 515 phases needed (t=511 for l=3 at p=514); rounded up to 516.
    for (int p = 0; p < 516; p += 2) {
        phase(p,     1, 0, xfA);      // even p: read buf1, write buf0
        phase(p + 1, 0, 1, xfB);      // odd  p: read buf0, write buf1
    }
}

// out = relu(last @ W1^T + b1) @ W2^T + b2   (f32, tiny)
__global__ __launch_bounds__(256)
void mlp_head(const float* __restrict__ last,
              const float* __restrict__ W1, const float* __restrict__ b1,
              const float* __restrict__ W2, const float* __restrict__ b2,
              float* __restrict__ out)
{
    __shared__ float sW1[128 * 64];
    __shared__ float sb1[128];
    __shared__ float sW2[3 * 128];
    __shared__ float sb2[4];
    const int tid = threadIdx.x;
    for (int i = tid; i < 128 * 64; i += 256) sW1[i] = W1[i];
    for (int i = tid; i < 128; i += 256) sb1[i] = b1[i];
    for (int i = tid; i < 3 * 128; i += 256) sW2[i] = W2[i];
    if (tid < 3) sb2[tid] = b2[tid];
    __syncthreads();

    const int b = blockIdx.x * 256 + tid;
    const float* lb = last + (size_t)b * 64;
    float xv[64];
#pragma unroll
    for (int k = 0; k < 64; k += 4) {
        f32x4 v = *(const f32x4*)(lb + k);
        xv[k] = v[0]; xv[k + 1] = v[1]; xv[k + 2] = v[2]; xv[k + 3] = v[3];
    }
    float o0 = sb2[0], o1 = sb2[1], o2 = sb2[2];
    for (int j = 0; j < 128; ++j) {
        float a = sb1[j];
        const float* wr = &sW1[j * 64];
#pragma unroll
        for (int k = 0; k < 64; k += 4) {
            f32x4 wv = *(const f32x4*)(wr + k);
            a += xv[k] * wv[0] + xv[k + 1] * wv[1] + xv[k + 2] * wv[2] + xv[k + 3] * wv[3];
        }
        a = fmaxf(a, 0.0f);
        o0 += a * sW2[0 * 128 + j];
        o1 += a * sW2[1 * 128 + j];
        o2 += a * sW2[2 * 128 + j];
    }
    out[(size_t)b * 3 + 0] = o0;
    out[(size_t)b * 3 + 1] = o1;
    out[(size_t)b * 3 + 2] = o2;
}

extern "C" void kernel_launch(void* const* d_in, const int* in_sizes, int n_in,
                              void* d_out, int out_size, void* d_ws, size_t ws_size,
                              hipStream_t stream)
{
    (void)in_sizes; (void)n_in; (void)out_size; (void)ws_size;

    const float* x = (const float*)d_in[0];
    WPtrs wp;
    for (int l = 0; l < 4; ++l) {
        wp.Wi[l] = (const float*)d_in[1 + 4 * l + 0];
        wp.Wh[l] = (const float*)d_in[1 + 4 * l + 1];
        wp.bi[l] = (const float*)d_in[1 + 4 * l + 2];
        wp.bh[l] = (const float*)d_in[1 + 4 * l + 3];
    }
    const float* W1 = (const float*)d_in[17];
    const float* b1 = (const float*)d_in[18];
    const float* W2 = (const float*)d_in[19];
    const float* b2 = (const float*)d_in[20];

    float* last = (float*)d_ws;                 // 2048*64 f32 = 512 KiB

    lstm_fused<<<dim3(256), dim3(1024), 0, stream>>>(x, last, wp);
    mlp_head<<<dim3(8), dim3(256), 0, stream>>>(last, W1, b1, W2, b2, (float*)d_out);
}

// Round 16
// 578.109 us; speedup vs baseline: 6.8991x; 1.0058x over previous
//
#include <hip/hip_runtime.h>
#include <stdint.h>

typedef __bf16 bf16_t;
typedef __bf16 bf16x8 __attribute__((ext_vector_type(8)));
typedef float  f32x4  __attribute__((ext_vector_type(4)));

union Frag { uint32_t u[4]; bf16x8 v; };

struct WPtrs {
    const float* Wi[4];
    const float* Wh[4];
    const float* bi[4];
    const float* bh[4];
};

#define LOG2E 1.44269504088896340736f

// Half-swap within each 16-lane DPP row: lane i <-> lane i^8 (row_ror:8).
__device__ __forceinline__ float dpp_halfswap(float x) {
    int i = __float_as_int(x);
    int r = __builtin_amdgcn_update_dpp(i, i, 0x128 /*row_ror:8*/, 0xF, 0xF, false);
    return __int_as_float(r);
}

// r16 = r14 (581 us verified) + ONE change: PAIRED RCP in the cell update.
// r15's G-chunk reorder broke at codegen level (source-identical dataflow,
// absmax 9.4e-2) -> abandoned. Remaining lever per the counter model
// (VALUBusy 63% = 1757 cyc/SIMD/phase, trans ~1100 of it at ~20 cyc each):
// cut trans count 14 -> 12 per wave via the 1/(ab) trick:
//   r = rcp(denA*denB); invA = r*denB; invB = r*denA
// applied to the c-pair and h-pair denominators (2 rcp saved, +6 mul).
// Overflow: den products < 1e18 for |gate| < ~22 natural units; observed
// activations are +-5 (absmax stable 4.88e-4 across 14 rounds). Math
// otherwise identical (prescaled exp2, shared-rcp algebra).
//
// Base structure (HW-verified r4-r14): fused 4-layer LSTM, layer-pipelined
// across 16 waves. Grid 256 blocks = batch tiles of 8 (MFMA N=16, cols 8..15
// pad; pad lanes repurposed via DPP half-swap: 2 REAL cells/lane).
// Block 1024 thr; wave w: layer l=w>>2, unit-quarter uq=w&3. Phase p: layer l
// computes t=p-l; 1 barrier/phase; lds_h double-buffered; x prefetch depth 2
// aliased onto dead wiA slots (reg demand ~123 < 128 cap, no spill).
__global__ __launch_bounds__(1024, 4)
void lstm_fused(const float* __restrict__ x0, float* __restrict__ last_out, WPtrs wp)
{
    const int tile = blockIdx.x;
    const int tid  = threadIdx.x;
    const int w    = tid >> 6;
    const int lane = tid & 63;
    const int l15  = lane & 15;
    const int l4   = lane >> 4;
    const int l    = w >> 2;
    const int uq   = w & 3;
    const bool hiH = (l15 >= 8);
    const int  col = l15 & 7;

    // [buf][layer][laneIdx][ut 0..3 + 2 pad] ; laneIdx = 16*l4 + col ; 24 KB
    __shared__ uint2 lds_h[2][4][64][6];

    for (int i = tid; i < 2 * 4 * 64 * 6; i += 1024)
        ((uint2*)lds_h)[i] = make_uint2(0u, 0u);

    const float* Wi = wp.Wi[l];
    const float* Wh = wp.Wh[l];

    // per-gate prescale: i,f,o -> log2e ; g -> 2*log2e
    const float gs[4] = {LOG2E, LOG2E, 2.0f * LOG2E, LOG2E};

    // ---- weight A-fragments (loop-invariant registers) ----
    // A-frag lane map (HW-verified): row = base + l15, k = 32*s + 4*l4 + j (+16 for j>=4)
    bf16x8 whA[4][2];
    bf16x8 wiA[4][2];
#pragma unroll
    for (int G = 0; G < 4; ++G) {
        const float sc = gs[G];
        const int row = G * 64 + 16 * uq + l15;
        const float* r = Wh + (size_t)row * 64;
#pragma unroll
        for (int s = 0; s < 2; ++s) {
            f32x4 a = *(const f32x4*)(r + 32 * s + 4 * l4);
            f32x4 b = *(const f32x4*)(r + 32 * s + 4 * l4 + 16);
            bf16x8 f;
            f[0] = (bf16_t)(a[0] * sc); f[1] = (bf16_t)(a[1] * sc);
            f[2] = (bf16_t)(a[2] * sc); f[3] = (bf16_t)(a[3] * sc);
            f[4] = (bf16_t)(b[0] * sc); f[5] = (bf16_t)(b[1] * sc);
            f[6] = (bf16_t)(b[2] * sc); f[7] = (bf16_t)(b[3] * sc);
            whA[G][s] = f;
        }
        if (l == 0) {
            const float* ri = Wi + (size_t)row * 18;     // K=18 padded to 32
            const int k0 = 4 * l4;
            bf16x8 f;
            f[0] = (bf16_t)(ri[k0 + 0] * sc); f[1] = (bf16_t)(ri[k0 + 1] * sc);
            f[2] = (bf16_t)(ri[k0 + 2] * sc); f[3] = (bf16_t)(ri[k0 + 3] * sc);
            f[4] = (l4 == 0) ? (bf16_t)(ri[16] * sc) : (bf16_t)0.0f;
            f[5] = (l4 == 0) ? (bf16_t)(ri[17] * sc) : (bf16_t)0.0f;
            f[6] = (bf16_t)0.0f; f[7] = (bf16_t)0.0f;
            wiA[G][0] = f;
            wiA[G][1] = f;   // placeholder; [2][1]/[3][1] become x buffers below
        } else {
            const float* ri = Wi + (size_t)row * 64;
#pragma unroll
            for (int s = 0; s < 2; ++s) {
                f32x4 a = *(const f32x4*)(ri + 32 * s + 4 * l4);
                f32x4 b = *(const f32x4*)(ri + 32 * s + 4 * l4 + 16);
                bf16x8 f;
                f[0] = (bf16_t)(a[0] * sc); f[1] = (bf16_t)(a[1] * sc);
                f[2] = (bf16_t)(a[2] * sc); f[3] = (bf16_t)(a[3] * sc);
                f[4] = (bf16_t)(b[0] * sc); f[5] = (bf16_t)(b[1] * sc);
                f[6] = (bf16_t)(b[2] * sc); f[7] = (bf16_t)(b[3] * sc);
                wiA[G][s] = f;
            }
        }
    }

    // ---- bias: ONLY the 8 post-swap scalars this lane consumes ----
    float biasA[4], biasB[4];
#pragma unroll
    for (int G = 0; G < 4; ++G) {
        const int rb = G * 64 + 16 * uq + 4 * l4 + (hiH ? 2 : 0);
        biasA[G] = (wp.bi[l][rb]     + wp.bh[l][rb])     * gs[G];
        biasB[G] = (wp.bi[l][rb + 1] + wp.bh[l][rb + 1]) * gs[G];
    }

    // ---- x prefetch (layer-0 waves), depth 2 ----
    // ALIASED onto wiA[2][1] / wiA[3][1]: dead slots for l==0, untouched by l>0.
    bf16x8& xfA = wiA[2][1];
    bf16x8& xfB = wiA[3][1];
    const int    xbatch = tile * 8 + (hiH ? 7 : col);
    const float* xrow   = x0 + (size_t)xbatch * (512 * 18);
    auto loadx = [&](int t, bf16x8& dst) {
        const float* xr = xrow + t * 18;
        const int k0 = 4 * l4;
        bf16x8 f;
        f[0] = (bf16_t)xr[k0 + 0]; f[1] = (bf16_t)xr[k0 + 1];
        f[2] = (bf16_t)xr[k0 + 2]; f[3] = (bf16_t)xr[k0 + 3];
        f[4] = (l4 == 0) ? (bf16_t)xr[16] : (bf16_t)0.0f;
        f[5] = (l4 == 0) ? (bf16_t)xr[17] : (bf16_t)0.0f;
        f[6] = (bf16_t)0.0f; f[7] = (bf16_t)0.0f;
        dst = f;
    };
    if (l == 0) { loadx(0, xfA); loadx(1, xfB); }

    float c0 = 0.0f, c1 = 0.0f;     // 2 real cells/lane

    __syncthreads();

    // br/bw arrive as LITERAL constants from the unrolled call sites.
    auto phase = [&](int p, int br, int bw, bf16x8& xf) {
        const int t = p - l;
        if (t >= 0 && t < 512) {
            const f32x4 z4 = {0.0f, 0.0f, 0.0f, 0.0f};
            f32x4 acc[4];

            // ---- x contribution (C starts at zero; bias added post-DPP) ----
            if (l == 0) {
#pragma unroll
                for (int G = 0; G < 4; ++G)
                    acc[G] = __builtin_amdgcn_mfma_f32_16x16x32_bf16(wiA[G][0], xf, z4, 0, 0, 0);
                loadx((t + 2) & 511, xf);       // prefetch 2 ahead (wrap harmless)
            } else {
                Frag b0, b1;
                {
                    uint4 q0 = *(const uint4*)&lds_h[br][l - 1][lane][0];
                    uint4 q1 = *(const uint4*)&lds_h[br][l - 1][lane][2];
                    b0.u[0] = q0.x; b0.u[1] = q0.y; b0.u[2] = q0.z; b0.u[3] = q0.w;
                    b1.u[0] = q1.x; b1.u[1] = q1.y; b1.u[2] = q1.z; b1.u[3] = q1.w;
                }
#pragma unroll
                for (int G = 0; G < 4; ++G)
                    acc[G] = __builtin_amdgcn_mfma_f32_16x16x32_bf16(wiA[G][0], b0.v, z4, 0, 0, 0);
#pragma unroll
                for (int G = 0; G < 4; ++G)
                    acc[G] = __builtin_amdgcn_mfma_f32_16x16x32_bf16(wiA[G][1], b1.v, acc[G], 0, 0, 0);
            }

            // ---- h contribution (own layer, t-1): 2 x ds_read_b128 ----
            {
                Frag h0, h1;
                uint4 q0 = *(const uint4*)&lds_h[br][l][lane][0];
                uint4 q1 = *(const uint4*)&lds_h[br][l][lane][2];
                h0.u[0] = q0.x; h0.u[1] = q0.y; h0.u[2] = q0.z; h0.u[3] = q0.w;
                h1.u[0] = q1.x; h1.u[1] = q1.y; h1.u[2] = q1.z; h1.u[3] = q1.w;
#pragma unroll
                for (int G = 0; G < 4; ++G)
                    acc[G] = __builtin_amdgcn_mfma_f32_16x16x32_bf16(whA[G][0], h0.v, acc[G], 0, 0, 0);
#pragma unroll
                for (int G = 0; G < 4; ++G)
                    acc[G] = __builtin_amdgcn_mfma_f32_16x16x32_bf16(whA[G][1], h1.v, acc[G], 0, 0, 0);
            }

            // ---- DPP half-swap: every lane gets 2 REAL cells; add bias here ----
            float g0[4], g1[4];
#pragma unroll
            for (int G = 0; G < 4; ++G) {
                const float s2 = dpp_halfswap(acc[G][2]);
                const float s3 = dpp_halfswap(acc[G][3]);
                g0[G] = (hiH ? s2 : acc[G][0]) + biasA[G];
                g1[G] = (hiH ? s3 : acc[G][1]) + biasB[G];
            }

            // ---- cell update: paired-rcp algebra (r16) ----
            // c' = [c*pi*pg + mg*pf] / [pf*pi*pg] ; one rcp for BOTH cells.
            const float eiA = __builtin_amdgcn_exp2f(-g0[0]);
            const float eiB = __builtin_amdgcn_exp2f(-g1[0]);
            const float efA = __builtin_amdgcn_exp2f(-g0[1]);
            const float efB = __builtin_amdgcn_exp2f(-g1[1]);
            const float EgA = __builtin_amdgcn_exp2f(g0[2]);
            const float EgB = __builtin_amdgcn_exp2f(g1[2]);
            const float piA = 1.0f + eiA, pfA = 1.0f + efA;
            const float piB = 1.0f + eiB, pfB = 1.0f + efB;
            const float pgA = EgA + 1.0f, mgA = EgA - 1.0f;
            const float pgB = EgB + 1.0f, mgB = EgB - 1.0f;
            const float qA   = piA * pgA;
            const float qB   = piB * pgB;
            const float numA = c0 * qA + mgA * pfA;
            const float numB = c1 * qB + mgB * pfB;
            const float denA = pfA * qA;
            const float denB = pfB * qB;
            const float rC   = __builtin_amdgcn_rcpf(denA * denB);
            const float cA   = numA * (rC * denB);
            const float cB   = numB * (rC * denA);
            c0 = cA; c1 = cB;
            // h = (Ec-1) / [(1+eo)*(Ec+1)] ; one rcp for BOTH cells.
            const float EcA = __builtin_amdgcn_exp2f(cA * (2.0f * LOG2E));
            const float EcB = __builtin_amdgcn_exp2f(cB * (2.0f * LOG2E));
            const float eoA = __builtin_amdgcn_exp2f(-g0[3]);
            const float eoB = __builtin_amdgcn_exp2f(-g1[3]);
            const float dA  = (1.0f + eoA) * (EcA + 1.0f);
            const float dB  = (1.0f + eoB) * (EcB + 1.0f);
            const float rH  = __builtin_amdgcn_rcpf(dA * dB);
            const float hA  = (EcA - 1.0f) * (rH * dB);
            const float hB  = (EcB - 1.0f) * (rH * dA);

            // ---- h writeback: one b32 per lane; pad laneIdx slots never written ----
            union { uint32_t u; bf16_t b[2]; } pk;
            pk.b[0] = (bf16_t)hA; pk.b[1] = (bf16_t)hB;
            uint32_t* slot = (uint32_t*)&lds_h[bw][l][16 * l4 + col][uq];
            slot[hiH ? 1 : 0] = pk.u;

            if (l == 3 && t == 511) {
                float* o = last_out + ((size_t)(tile * 8 + col)) * 64
                           + 16 * uq + 4 * l4 + (hiH ? 2 : 0);
                *(float2*)o = make_float2(hA, hB);
            }
        }
        __syncthreads();
    };

    // 515 phases needed (t=511 for l=3 at p=514); rounded up to 516.
    for (int p = 0; p < 516; p += 2) {
        phase(p,     1, 0, xfA);      // even p: read buf1, write buf0
        phase(p + 1, 0, 1, xfB);      // odd  p: read buf0, write buf1
    }
}

// out = relu(last @ W1^T + b1) @ W2^T + b2   (f32, tiny)
__global__ __launch_bounds__(256)
void mlp_head(const float* __restrict__ last,
              const float* __restrict__ W1, const float* __restrict__ b1,
              const float* __restrict__ W2, const float* __restrict__ b2,
              float* __restrict__ out)
{
    __shared__ float sW1[128 * 64];
    __shared__ float sb1[128];
    __shared__ float sW2[3 * 128];
    __shared__ float sb2[4];
    const int tid = threadIdx.x;
    for (int i = tid; i < 128 * 64; i += 256) sW1[i] = W1[i];
    for (int i = tid; i < 128; i += 256) sb1[i] = b1[i];
    for (int i = tid; i < 3 * 128; i += 256) sW2[i] = W2[i];
    if (tid < 3) sb2[tid] = b2[tid];
    __syncthreads();

    const int b = blockIdx.x * 256 + tid;
    const float* lb = last + (size_t)b * 64;
    float xv[64];
#pragma unroll
    for (int k = 0; k < 64; k += 4) {
        f32x4 v = *(const f32x4*)(lb + k);
        xv[k] = v[0]; xv[k + 1] = v[1]; xv[k + 2] = v[2]; xv[k + 3] = v[3];
    }
    float o0 = sb2[0], o1 = sb2[1], o2 = sb2[2];
    for (int j = 0; j < 128; ++j) {
        float a = sb1[j];
        const float* wr = &sW1[j * 64];
#pragma unroll
        for (int k = 0; k < 64; k += 4) {
            f32x4 wv = *(const f32x4*)(wr + k);
            a += xv[k] * wv[0] + xv[k + 1] * wv[1] + xv[k + 2] * wv[2] + xv[k + 3] * wv[3];
        }
        a = fmaxf(a, 0.0f);
        o0 += a * sW2[0 * 128 + j];
        o1 += a * sW2[1 * 128 + j];
        o2 += a * sW2[2 * 128 + j];
    }
    out[(size_t)b * 3 + 0] = o0;
    out[(size_t)b * 3 + 1] = o1;
    out[(size_t)b * 3 + 2] = o2;
}

extern "C" void kernel_launch(void* const* d_in, const int* in_sizes, int n_in,
                              void* d_out, int out_size, void* d_ws, size_t ws_size,
                              hipStream_t stream)
{
    (void)in_sizes; (void)n_in; (void)out_size; (void)ws_size;

    const float* x = (const float*)d_in[0];
    WPtrs wp;
    for (int l = 0; l < 4; ++l) {
        wp.Wi[l] = (const float*)d_in[1 + 4 * l + 0];
        wp.Wh[l] = (const float*)d_in[1 + 4 * l + 1];
        wp.bi[l] = (const float*)d_in[1 + 4 * l + 2];
        wp.bh[l] = (const float*)d_in[1 + 4 * l + 3];
    }
    const float* W1 = (const float*)d_in[17];
    const float* b1 = (const float*)d_in[18];
    const float* W2 = (const float*)d_in[19];
    const float* b2 = (const float*)d_in[20];

    float* last = (float*)d_ws;                 // 2048*64 f32 = 512 KiB

    lstm_fused<<<dim3(256), dim3(1024), 0, stream>>>(x, last, wp);
    mlp_head<<<dim3(8), dim3(256), 0, stream>>>(last, W1, b1, W2, b2, (float*)d_out);
}